// Round 3
// baseline (330.544 us; speedup 1.0000x reference)
//
#include <hip/hip_runtime.h>
#include <math.h>

#define N_SEQ 384
#define DIM 512
#define BATCH 8
#define M_ROWS (BATCH * N_SEQ)   // 3072
#define QK_COLS (2 * DIM)        // 1024: cols 0..511 = q, 512..1023 = k
#define TI 16                    // rows per fused-score block

typedef short v8s __attribute__((ext_vector_type(8)));   // 8 bf16 (4 VGPRs)
typedef float v4f __attribute__((ext_vector_type(4)));   // MFMA f32 acc

__device__ inline unsigned short f2bf(float f) {
    union { float f; unsigned u; } c; c.f = f;
    unsigned u = c.u;
    u += 0x7fffu + ((u >> 16) & 1u);   // RNE (inputs finite)
    return (unsigned short)(u >> 16);
}

// ---------------------------------------------------------------------------
// Kernel 0: cast h / Wq / Wk (fp32) -> bf16. One float4 per thread.
// ---------------------------------------------------------------------------
#define H_F4 ((M_ROWS * DIM) / 4)   // 393216
#define W_F4 ((DIM * DIM) / 4)      // 65536
__global__ __launch_bounds__(256) void cast_inputs(
    const float* __restrict__ h, const float* __restrict__ Wq,
    const float* __restrict__ Wk, unsigned short* __restrict__ h_bf,
    unsigned short* __restrict__ w_bf)
{
    const int idx = blockIdx.x * 256 + threadIdx.x;
    const float4* src; unsigned short* dst; size_t off;
    if (idx < H_F4)             { src = (const float4*)h;  dst = h_bf;                     off = idx; }
    else if (idx < H_F4 + W_F4) { src = (const float4*)Wq; dst = w_bf;                     off = idx - H_F4; }
    else                        { src = (const float4*)Wk; dst = w_bf + (size_t)DIM * DIM; off = idx - H_F4 - W_F4; }
    float4 v = src[off];
    ushort4 o;
    o.x = f2bf(v.x); o.y = f2bf(v.y); o.z = f2bf(v.z); o.w = f2bf(v.w);
    *(ushort4*)(dst + off * 4) = o;
}

// ---------------------------------------------------------------------------
// Kernel 1: MFMA qk projection.  qk_bf[3072x1024] = h_bf @ [Wq;Wk]^T (+bq on
// the q half).  128x128 tile, 4 waves, each 64x64 = 4x4 of 16x16x32.
// LDS rows padded to 40 bf16: bank stride 20 -> 2-way aliasing (free, m136).
// ---------------------------------------------------------------------------
__global__ __launch_bounds__(256) void qk_gemm(
    const unsigned short* __restrict__ A,   // h_bf 3072x512
    const unsigned short* __restrict__ Bm,  // w_bf 1024x512
    const float* __restrict__ bq,
    unsigned short* __restrict__ C)         // qk_bf 3072x1024
{
    __shared__ unsigned short As[128][40];
    __shared__ unsigned short Bs[128][40];
    const int bm = blockIdx.x * 128;
    const int bn = blockIdx.y * 128;
    const int t = threadIdx.x;
    const int wv = t >> 6, lane = t & 63;
    const int wm = (wv & 1) * 64, wn = (wv >> 1) * 64;
    const int lm = lane & 15, quad = lane >> 4;
    const int srow = t >> 2, skc = (t & 3) * 8;
    v4f acc[4][4] = {};
    for (int k0 = 0; k0 < DIM; k0 += 32) {
        v8s a0 = *(const v8s*)(A  + (size_t)(bm + srow)      * DIM + k0 + skc);
        v8s a1 = *(const v8s*)(A  + (size_t)(bm + srow + 64) * DIM + k0 + skc);
        v8s b0 = *(const v8s*)(Bm + (size_t)(bn + srow)      * DIM + k0 + skc);
        v8s b1 = *(const v8s*)(Bm + (size_t)(bn + srow + 64) * DIM + k0 + skc);
        __syncthreads();
        *(v8s*)&As[srow][skc]      = a0;
        *(v8s*)&As[srow + 64][skc] = a1;
        *(v8s*)&Bs[srow][skc]      = b0;
        *(v8s*)&Bs[srow + 64][skc] = b1;
        __syncthreads();
        v8s af[4], bf[4];
#pragma unroll
        for (int i = 0; i < 4; ++i) af[i] = *(const v8s*)&As[wm + i * 16 + lm][quad * 8];
#pragma unroll
        for (int j = 0; j < 4; ++j) bf[j] = *(const v8s*)&Bs[wn + j * 16 + lm][quad * 8];
#pragma unroll
        for (int i = 0; i < 4; ++i)
#pragma unroll
            for (int j = 0; j < 4; ++j)
                acc[i][j] = __builtin_amdgcn_mfma_f32_16x16x32_bf16(af[i], bf[j], acc[i][j], 0, 0, 0);
    }
#pragma unroll
    for (int i = 0; i < 4; ++i)
#pragma unroll
        for (int j = 0; j < 4; ++j) {
            const int col = bn + wn + j * 16 + lm;
            const float bias = (col < DIM) ? bq[col] : 0.f;
#pragma unroll
            for (int r = 0; r < 4; ++r) {
                const int row = bm + wm + i * 16 + quad * 4 + r;
                C[(size_t)row * QK_COLS + col] = f2bf(acc[i][j][r] + bias);
            }
        }
}

// ---------------------------------------------------------------------------
// Kernel 2: fully fused scores + d-term + clip + log-sigmoid + prefix-scan +
// interval lookup.  Block = 16 query rows x all 384 key cols for one batch.
// grid (24, 8).  raw lives only in LDS; uses lp = x + l1 identity.
// LDS union: staging (As 16x40 + Bs 384x40 bf16 = 32000 B)  <->
//            phase3 (raw 16x385 f32 = 24640 B + P 4x385 f32 = 6160 B).
// ---------------------------------------------------------------------------
__global__ __launch_bounds__(256) void score_finalize(
    const unsigned short* __restrict__ QK, const float* __restrict__ h,
    const float* __restrict__ wlr, const float* __restrict__ blr,
    const float* __restrict__ wrl, const float* __restrict__ brl,
    const float* __restrict__ alpha, const float* __restrict__ beta,
    const float* __restrict__ gamma, const float* __restrict__ mask,
    float* __restrict__ out_r, float* __restrict__ out_am)
{
    __shared__ __align__(16) char smem[32000];
    __shared__ float lrL[TI], lrR[TI];
    unsigned short (*As)[40]  = (unsigned short(*)[40])smem;           // 16x40
    unsigned short (*Bs)[40]  = (unsigned short(*)[40])(smem + 1280);  // 384x40
    float (*rawS)[385]        = (float(*)[385])smem;                   // 16x385
    float (*P)[385]           = (float(*)[385])(smem + 24640);         // 4x385

    const int b  = blockIdx.y;
    const int i0 = blockIdx.x * TI;
    const int t  = threadIdx.x;
    const int wv = t >> 6, lane = t & 63;
    const int lm = lane & 15, quad = lane >> 4;

    // ---- Phase 0: left/right GEMVs for our 16 rows (wave wv: rows wv*4..+3)
#pragma unroll
    for (int rr = 0; rr < 4; ++rr) {
        const int r = wv * 4 + rr;
        const float* hr = h + (size_t)(b * N_SEQ + i0 + r) * DIM;
        float sl = 0.f, sr = 0.f;
        for (int c = lane; c < DIM; c += 64) {
            const float hv = hr[c];
            sl = fmaf(hv, wlr[c], sl);
            sr = fmaf(hv, wrl[c], sr);
        }
#pragma unroll
        for (int off = 32; off > 0; off >>= 1) {
            sl += __shfl_down(sl, off);
            sr += __shfl_down(sr, off);
        }
        if (lane == 0) { lrL[r] = sl + blr[0]; lrR[r] = sr + brl[0]; }
    }

    // ---- Phase 1: S = q_rows @ k_all^T  (16 x 384), BK=32.
    // wave wv owns j-tiles wv*6 .. wv*6+5 (16 cols each).
    v4f acc[6] = {};
    const unsigned short* qbase = QK + (size_t)(b * N_SEQ + i0) * QK_COLS;
    const unsigned short* kbase = QK + (size_t)(b * N_SEQ) * QK_COLS + DIM;
    const int srow = t >> 2, skc = (t & 3) * 8;
    for (int k0 = 0; k0 < DIM; k0 += 32) {
        v8s breg[6];
#pragma unroll
        for (int s = 0; s < 6; ++s)
            breg[s] = *(const v8s*)(kbase + (size_t)(s * 64 + srow) * QK_COLS + k0 + skc);
        v8s areg = {};
        if (t < 64) areg = *(const v8s*)(qbase + (size_t)(t >> 2) * QK_COLS + k0 + skc);
        __syncthreads();   // previous iter's ds_reads (and phase-0 lr writes) done
#pragma unroll
        for (int s = 0; s < 6; ++s) *(v8s*)&Bs[s * 64 + srow][skc] = breg[s];
        if (t < 64) *(v8s*)&As[t >> 2][skc] = areg;
        __syncthreads();
        const v8s af = *(const v8s*)&As[lm][quad * 8];
#pragma unroll
        for (int j = 0; j < 6; ++j) {
            const v8s bf = *(const v8s*)&Bs[(wv * 6 + j) * 16 + lm][quad * 8];
            acc[j] = __builtin_amdgcn_mfma_f32_16x16x32_bf16(af, bf, acc[j], 0, 0, 0);
        }
    }
    __syncthreads();   // staging dead; rawS may now overwrite it

    // ---- Phase 2: epilogue -> raw in LDS
    const float al = alpha[0], be = beta[0], ga = gamma[0];
#pragma unroll
    for (int j = 0; j < 6; ++j) {
        const int col = (wv * 6 + j) * 16 + lm;
#pragma unroll
        for (int r4 = 0; r4 < 4; ++r4) {
            const int rloc = quad * 4 + r4;
            const int ig = i0 + rloc;
            const float dterm = (col >= ig) ? lrL[rloc] : lrR[rloc];
            float v = fmaf(al, acc[j][r4], fmaf(be, dterm, ga));
            v = fminf(fmaxf(v, -16.f), 14.f);
            rawS[rloc][col] = v;
        }
    }
    __syncthreads();

    // ---- Phase 3: per-row scan + interval lookup.  Wave wv: rows wv*4..+3,
    // lane covers cols lane*6..lane*6+5.  l1 = log(1-sigmoid(x)); lp = x + l1.
#pragma unroll
    for (int rr = 0; rr < 4; ++rr) {
        const int rloc = wv * 4 + rr;
        const int ig = i0 + rloc;
        float x[6], l1[6], s6[6];
        float T = 0.f;
#pragma unroll
        for (int c = 0; c < 6; ++c) {
            x[c] = rawS[rloc][lane * 6 + c];
            l1[c] = -log1pf(expf(x[c]));
            T += l1[c];
            s6[c] = T;
        }
        float incl = T;
#pragma unroll
        for (int off = 1; off < 64; off <<= 1) {
            const float tt = __shfl_up(incl, off);
            if (lane >= off) incl += tt;
        }
        const float E = incl - T;   // exclusive wave prefix
#pragma unroll
        for (int c = 0; c < 6; ++c) P[wv][1 + lane * 6 + c] = E + s6[c];
        if (lane == 0) P[wv][0] = 0.f;
        __syncthreads();
        const float maskbi = mask[b * N_SEQ + ig];
#pragma unroll
        for (int c = 0; c < 6; ++c) {
            const int j = lane * 6 + c;
            float S = 0.f;
            if (ig < j) {
                int lo2 = 2 * ig - j + 1; if (lo2 < 0) lo2 = 0;
                S = (P[wv][j] - P[wv][ig + 1]) + (P[wv][ig] - P[wv][lo2]);
            } else if (ig > j) {
                int hi2 = 2 * ig - j + 1; if (hi2 > N_SEQ) hi2 = N_SEQ;
                S = (P[wv][ig] - P[wv][j + 1]) + (P[wv][hi2] - P[wv][ig + 1]);
            }
            float rv = S + (x[c] + l1[c]);
            if (ig == j) rv -= 10000.f;
            const size_t o = (size_t)(b * N_SEQ + ig) * N_SEQ + j;
            out_r[o]  = rv;
            out_am[o] = maskbi * mask[b * N_SEQ + j];
        }
        __syncthreads();   // P reused next row
    }
}

// ---------------------------------------------------------------------------
extern "C" void kernel_launch(void* const* d_in, const int* in_sizes, int n_in,
                              void* d_out, int out_size, void* d_ws, size_t ws_size,
                              hipStream_t stream) {
    const float* h     = (const float*)d_in[0];
    const float* mask  = (const float*)d_in[1];
    const float* Wq    = (const float*)d_in[2];
    const float* bq    = (const float*)d_in[3];
    const float* Wk    = (const float*)d_in[4];
    const float* wlr   = (const float*)d_in[5];
    const float* blr   = (const float*)d_in[6];
    const float* wrl   = (const float*)d_in[7];
    const float* brl   = (const float*)d_in[8];
    const float* alpha = (const float*)d_in[9];
    const float* beta  = (const float*)d_in[10];
    const float* gamma = (const float*)d_in[11];
    // d_in[12] (masking_matrix) intentionally unused: analytic k-intervals +
    // prefix sum replace the O(N^3) einsum.

    unsigned short* h_bf  = (unsigned short*)d_ws;                 // 3072x512
    unsigned short* w_bf  = h_bf + (size_t)M_ROWS * DIM;           // 1024x512
    unsigned short* qk_bf = w_bf + (size_t)QK_COLS * DIM;          // 3072x1024

    float* out_r  = (float*)d_out;
    float* out_am = out_r + (size_t)BATCH * N_SEQ * N_SEQ;

    cast_inputs<<<(H_F4 + 2 * W_F4) / 256, 256, 0, stream>>>(h, Wq, Wk, h_bf, w_bf);
    dim3 g1(M_ROWS / 128, QK_COLS / 128);       // 24 x 8
    qk_gemm<<<g1, 256, 0, stream>>>(h_bf, w_bf, bq, qk_bf);
    dim3 g2(N_SEQ / TI, BATCH);                 // 24 x 8
    score_finalize<<<g2, 256, 0, stream>>>(qk_bf, h, wlr, blr, wrl, brl,
                                           alpha, beta, gamma, mask, out_r, out_am);
}

// Round 4
// 306.420 us; speedup vs baseline: 1.0787x; 1.0787x over previous
//
#include <hip/hip_runtime.h>
#include <math.h>

#define N_SEQ 384
#define DIM 512
#define BATCH 8
#define M_ROWS (BATCH * N_SEQ)   // 3072
#define QK_COLS (2 * DIM)        // 1024: cols 0..511 = q, 512..1023 = k

typedef short v8s __attribute__((ext_vector_type(8)));   // 8 bf16 (4 VGPRs)
typedef float v4f __attribute__((ext_vector_type(4)));   // MFMA f32 acc

__device__ inline unsigned short f2bf(float f) {
    union { float f; unsigned u; } c; c.f = f;
    unsigned u = c.u;
    u += 0x7fffu + ((u >> 16) & 1u);   // RNE (inputs finite)
    return (unsigned short)(u >> 16);
}

// ---------------------------------------------------------------------------
// Kernel 0: prep = cast h/Wq/Wk -> bf16  +  left/right GEMVs, fused.
// One wave per 512-elem row.  Wave-tasks 0..3071 = h rows (cast + GEMV),
// 3072..4095 = Wq/Wk rows (cast only).  Grid 1024 x 256.
// ---------------------------------------------------------------------------
__global__ __launch_bounds__(256) void prep(
    const float* __restrict__ h, const float* __restrict__ Wq,
    const float* __restrict__ Wk, const float* __restrict__ wlr,
    const float* __restrict__ blr, const float* __restrict__ wrl,
    const float* __restrict__ brl, unsigned short* __restrict__ h_bf,
    unsigned short* __restrict__ w_bf, float* __restrict__ left,
    float* __restrict__ right)
{
    const int wv = threadIdx.x >> 6, lane = threadIdx.x & 63;
    const int task = blockIdx.x * 4 + wv;          // 0..4095
    const float* src; unsigned short* dst;
    if (task < M_ROWS) {
        src = h + (size_t)task * DIM;
        dst = h_bf + (size_t)task * DIM;
    } else {
        const int r = task - M_ROWS;               // 0..1023
        src = (r < DIM) ? (Wq + (size_t)r * DIM) : (Wk + (size_t)(r - DIM) * DIM);
        dst = w_bf + (size_t)r * DIM;
    }
    const float4* s4 = (const float4*)src;
    const float4 v0 = s4[lane];        // elems lane*4 .. +3
    const float4 v1 = s4[lane + 64];   // elems 256+lane*4 .. +3
    ushort4 o0, o1;
    o0.x = f2bf(v0.x); o0.y = f2bf(v0.y); o0.z = f2bf(v0.z); o0.w = f2bf(v0.w);
    o1.x = f2bf(v1.x); o1.y = f2bf(v1.y); o1.z = f2bf(v1.z); o1.w = f2bf(v1.w);
    *(ushort4*)(dst + lane * 4)       = o0;
    *(ushort4*)(dst + 256 + lane * 4) = o1;
    if (task < M_ROWS) {
        const float4* wl4 = (const float4*)wlr;
        const float4* wr4 = (const float4*)wrl;
        const float4 a0 = wl4[lane], a1 = wl4[lane + 64];
        const float4 c0 = wr4[lane], c1 = wr4[lane + 64];
        float sl = v0.x * a0.x + v0.y * a0.y + v0.z * a0.z + v0.w * a0.w
                 + v1.x * a1.x + v1.y * a1.y + v1.z * a1.z + v1.w * a1.w;
        float sr = v0.x * c0.x + v0.y * c0.y + v0.z * c0.z + v0.w * c0.w
                 + v1.x * c1.x + v1.y * c1.y + v1.z * c1.z + v1.w * c1.w;
#pragma unroll
        for (int off = 32; off > 0; off >>= 1) {
            sl += __shfl_down(sl, off);
            sr += __shfl_down(sr, off);
        }
        if (lane == 0) {
            left[task]  = sl + blr[0];
            right[task] = sr + brl[0];
        }
    }
}

// ---------------------------------------------------------------------------
// Kernel 1: MFMA qk projection, 64x64 tile (grid 48x16 = 768 blocks, 3/CU for
// latency hiding).  qk_bf[3072x1024] = h_bf @ [Wq;Wk]^T (+bq on q half).
// 4 waves, each 32x32 = 2x2 of 16x16x32.  LDS rows padded to 40 bf16.
// ---------------------------------------------------------------------------
__global__ __launch_bounds__(256) void qk_gemm(
    const unsigned short* __restrict__ A,   // h_bf 3072x512
    const unsigned short* __restrict__ Bm,  // w_bf 1024x512
    const float* __restrict__ bq,
    unsigned short* __restrict__ C)         // qk_bf 3072x1024
{
    __shared__ unsigned short As[64][40];
    __shared__ unsigned short Bs[64][40];
    const int bm = blockIdx.x * 64;
    const int bn = blockIdx.y * 64;
    const int t = threadIdx.x;
    const int wv = t >> 6, lane = t & 63;
    const int wm = (wv & 1) * 32, wn = (wv >> 1) * 32;
    const int lm = lane & 15, quad = lane >> 4;
    const int srow = t >> 2, skc = (t & 3) * 8;
    v4f acc[2][2] = {};
    for (int k0 = 0; k0 < DIM; k0 += 32) {
        v8s a0 = *(const v8s*)(A  + (size_t)(bm + srow) * DIM + k0 + skc);
        v8s b0 = *(const v8s*)(Bm + (size_t)(bn + srow) * DIM + k0 + skc);
        __syncthreads();
        *(v8s*)&As[srow][skc] = a0;
        *(v8s*)&Bs[srow][skc] = b0;
        __syncthreads();
        v8s af[2], bf[2];
#pragma unroll
        for (int i = 0; i < 2; ++i) af[i] = *(const v8s*)&As[wm + i * 16 + lm][quad * 8];
#pragma unroll
        for (int j = 0; j < 2; ++j) bf[j] = *(const v8s*)&Bs[wn + j * 16 + lm][quad * 8];
#pragma unroll
        for (int i = 0; i < 2; ++i)
#pragma unroll
            for (int j = 0; j < 2; ++j)
                acc[i][j] = __builtin_amdgcn_mfma_f32_16x16x32_bf16(af[i], bf[j], acc[i][j], 0, 0, 0);
    }
#pragma unroll
    for (int i = 0; i < 2; ++i)
#pragma unroll
        for (int j = 0; j < 2; ++j) {
            const int col = bn + wn + j * 16 + lm;
            const float bias = (col < DIM) ? bq[col] : 0.f;
#pragma unroll
            for (int r = 0; r < 4; ++r) {
                const int row = bm + wm + i * 16 + quad * 4 + r;
                C[(size_t)row * QK_COLS + col] = f2bf(acc[i][j][r] + bias);
            }
        }
}

// ---------------------------------------------------------------------------
// Kernel 2: MFMA batched scores q_b @ k_b^T fused with
// raw = clip(alpha*s + beta*d + gamma).  64x64 tile, grid 6x6x8 = 288 blocks.
// ---------------------------------------------------------------------------
__global__ __launch_bounds__(256) void score_gemm(
    const unsigned short* __restrict__ QK, const float* __restrict__ left,
    const float* __restrict__ right, const float* __restrict__ alpha,
    const float* __restrict__ beta, const float* __restrict__ gamma,
    float* __restrict__ raw)
{
    __shared__ unsigned short As[64][40];
    __shared__ unsigned short Bs[64][40];
    const int b  = blockIdx.z;
    const int bi = blockIdx.x * 64, bj = blockIdx.y * 64;
    const int t = threadIdx.x;
    const int wv = t >> 6, lane = t & 63;
    const int wm = (wv & 1) * 32, wn = (wv >> 1) * 32;
    const int lm = lane & 15, quad = lane >> 4;
    const int srow = t >> 2, skc = (t & 3) * 8;
    const unsigned short* qb = QK + (size_t)(b * N_SEQ) * QK_COLS;
    v4f acc[2][2] = {};
    for (int k0 = 0; k0 < DIM; k0 += 32) {
        v8s a0 = *(const v8s*)(qb + (size_t)(bi + srow) * QK_COLS + k0 + skc);
        v8s b0 = *(const v8s*)(qb + (size_t)(bj + srow) * QK_COLS + DIM + k0 + skc);
        __syncthreads();
        *(v8s*)&As[srow][skc] = a0;
        *(v8s*)&Bs[srow][skc] = b0;
        __syncthreads();
        v8s af[2], bf[2];
#pragma unroll
        for (int i = 0; i < 2; ++i) af[i] = *(const v8s*)&As[wm + i * 16 + lm][quad * 8];
#pragma unroll
        for (int j = 0; j < 2; ++j) bf[j] = *(const v8s*)&Bs[wn + j * 16 + lm][quad * 8];
#pragma unroll
        for (int i = 0; i < 2; ++i)
#pragma unroll
            for (int j = 0; j < 2; ++j)
                acc[i][j] = __builtin_amdgcn_mfma_f32_16x16x32_bf16(af[i], bf[j], acc[i][j], 0, 0, 0);
    }
    const float al = alpha[0], be = beta[0], ga = gamma[0];
#pragma unroll
    for (int i = 0; i < 2; ++i)
#pragma unroll
        for (int j = 0; j < 2; ++j) {
            const int jcol = bj + wn + j * 16 + lm;
#pragma unroll
            for (int r = 0; r < 4; ++r) {
                const int irow = bi + wm + i * 16 + quad * 4 + r;
                const float lv = left[b * N_SEQ + irow];
                const float rv = right[b * N_SEQ + irow];
                const float dterm = (jcol >= irow) ? lv : rv;
                float v = fmaf(al, acc[i][j][r], fmaf(be, dterm, ga));
                v = fminf(fmaxf(v, -16.f), 14.f);
                raw[((size_t)b * N_SEQ + irow) * N_SEQ + jcol] = v;
            }
        }
}

// ---------------------------------------------------------------------------
// Kernel 3: per (b,i) row finalize.  Recomputes l1 = log(1-sigmoid(x)) and
// lp = x + l1, prefix-scans l1, evaluates the two analytic mask intervals:
//   i<j: (P[j]-P[i+1]) + (P[i]-P[max(2i-j+1,0)])
//   i>j: (P[i]-P[j+1]) + (P[min(2i-j+1,N)]-P[i+1])
// Grid 384x8 = 3072 blocks.  masking_matrix input never touched.
// ---------------------------------------------------------------------------
__global__ __launch_bounds__(384) void finalize(
    const float* __restrict__ raw, const float* __restrict__ mask,
    float* __restrict__ out_r, float* __restrict__ out_am)
{
    const int n = N_SEQ;
    const int i = blockIdx.x;
    const int b = blockIdx.y;
    const int j = threadIdx.x;     // 0..383
    __shared__ float P[N_SEQ + 1];
    __shared__ float wsum[6];
    const float x  = raw[((size_t)b * n + i) * n + j];
    const float l1 = -log1pf(expf(x));    // log(1 - sigmoid(x))
    const float lp = x + l1;              // log sigmoid(x)
    const int lane = j & 63, w = j >> 6;
    float v = l1;
#pragma unroll
    for (int off = 1; off < 64; off <<= 1) {
        const float tt = __shfl_up(v, off);
        if (lane >= off) v += tt;
    }
    if (lane == 63) wsum[w] = v;
    __syncthreads();
    float woff = 0.f;
    for (int t = 0; t < w; ++t) woff += wsum[t];
    P[j + 1] = v + woff;
    if (j == 0) P[0] = 0.f;
    __syncthreads();
    float s = 0.f;
    if (i < j) {
        int lo2 = 2 * i - j + 1; if (lo2 < 0) lo2 = 0;
        s = (P[j] - P[i + 1]) + (P[i] - P[lo2]);
    } else if (i > j) {
        int hi2 = 2 * i - j + 1; if (hi2 > n) hi2 = n;
        s = (P[i] - P[j + 1]) + (P[hi2] - P[i + 1]);
    }
    float r = s + lp;
    if (i == j) r -= 10000.f;
    const size_t o = ((size_t)b * n + i) * n + j;
    out_r[o]  = r;
    out_am[o] = mask[b * n + i] * mask[b * n + j];
}

// ---------------------------------------------------------------------------
extern "C" void kernel_launch(void* const* d_in, const int* in_sizes, int n_in,
                              void* d_out, int out_size, void* d_ws, size_t ws_size,
                              hipStream_t stream) {
    const float* h     = (const float*)d_in[0];
    const float* mask  = (const float*)d_in[1];
    const float* Wq    = (const float*)d_in[2];
    const float* bq    = (const float*)d_in[3];
    const float* Wk    = (const float*)d_in[4];
    const float* wlr   = (const float*)d_in[5];
    const float* blr   = (const float*)d_in[6];
    const float* wrl   = (const float*)d_in[7];
    const float* brl   = (const float*)d_in[8];
    const float* alpha = (const float*)d_in[9];
    const float* beta  = (const float*)d_in[10];
    const float* gamma = (const float*)d_in[11];
    // d_in[12] (masking_matrix) intentionally unused: analytic k-intervals +
    // prefix sum replace the O(N^3) einsum.

    unsigned short* h_bf  = (unsigned short*)d_ws;                 // 3072x512
    unsigned short* w_bf  = h_bf + (size_t)M_ROWS * DIM;           // 1024x512
    unsigned short* qk_bf = w_bf + (size_t)QK_COLS * DIM;          // 3072x1024
    float* left  = (float*)(qk_bf + (size_t)M_ROWS * QK_COLS);     // 3072
    float* right = left + M_ROWS;                                  // 3072
    float* raw   = right + M_ROWS;                                 // 8*384*384

    float* out_r  = (float*)d_out;
    float* out_am = out_r + (size_t)BATCH * N_SEQ * N_SEQ;

    prep<<<1024, 256, 0, stream>>>(h, Wq, Wk, wlr, blr, wrl, brl,
                                   h_bf, w_bf, left, right);
    dim3 g1(M_ROWS / 64, QK_COLS / 64);         // 48 x 16
    qk_gemm<<<g1, 256, 0, stream>>>(h_bf, w_bf, bq, qk_bf);
    dim3 g2(N_SEQ / 64, N_SEQ / 64, BATCH);     // 6 x 6 x 8
    score_gemm<<<g2, 256, 0, stream>>>(qk_bf, left, right, alpha, beta, gamma, raw);
    dim3 g3(N_SEQ, BATCH);
    finalize<<<g3, 384, 0, stream>>>(raw, mask, out_r, out_am);
}